// Round 3
// baseline (249.559 us; speedup 1.0000x reference)
//
#include <hip/hip_runtime.h>
#include <math.h>

#define IMG 509
#define C1N 253
#define C2N 125
#define NSPH 512   // SPHERE_FDIM
#define NY 64      // SO3_F1
#define NK 192     // kernel-grid points
#define NH 25      // (LMAX+1)^2
#define NI 165     // sum (2l+1)^2
#define NG 576     // activation grid
#define NE 4608    // eval grid
#define NP 20      // projector points
#define YN 12288   // NY*NK
#define PSPLIT 16  // k_proj hw splits

// decode flat irrep index t in [0,165) -> (l, offset, d, row u, col m)
__device__ __forceinline__ void decode_irr(int t, int& l, int& o, int& d, int& u, int& m) {
    if (t < 1)       { l = 0; o = 0;  }
    else if (t < 10) { l = 1; o = 1;  }
    else if (t < 35) { l = 2; o = 10; }
    else if (t < 84) { l = 3; o = 35; }
    else             { l = 4; o = 84; }
    d = 2 * l + 1;
    int r = t - o;
    u = r / d;
    m = r - u * d;
}

// ---- fused conv1(stride2)+relu+conv2(stride2), batch sample 0 only ----
// grid (8,8): 16x16 tile of conv2 outputs per block; conv1 tile 35x35x3 in LDS
__global__ __launch_bounds__(256) void k_conv(const float* __restrict__ x,
        const float* __restrict__ w1, const float* __restrict__ b1,
        const float* __restrict__ w2, const float* __restrict__ b2,
        float* __restrict__ f0) {
    __shared__ float s1[3][35][36];   // +1 pad
    __shared__ float sw1[75];
    __shared__ float sw2[375];
    int tid = threadIdx.x;
    if (tid < 75) sw1[tid] = w1[tid];
    for (int j = tid; j < 375; j += 256) sw2[j] = w2[j];
    int OH0 = blockIdx.y * 16, OW0 = blockIdx.x * 16;
    int R0 = 2 * OH0, C0 = 2 * OW0;
    float bb0 = b1[0], bb1 = b1[1], bb2 = b1[2];
    __syncthreads();
    // phase 1: conv1 + relu into LDS
    for (int j = tid; j < 35 * 35; j += 256) {
        int rr = j / 35, cc = j - rr * 35;
        int r = R0 + rr, c = C0 + cc;
        float v0 = 0.f, v1 = 0.f, v2 = 0.f;
        if (r < C1N && c < C1N) {
            const float* xp = x + (2 * r) * IMG + 2 * c;
            float a0 = bb0, a1 = bb1, a2 = bb2;
#pragma unroll
            for (int kh = 0; kh < 5; ++kh)
#pragma unroll
                for (int kw = 0; kw < 5; ++kw) {
                    float xv = xp[kh * IMG + kw];
                    a0 = fmaf(xv, sw1[kh * 5 + kw], a0);
                    a1 = fmaf(xv, sw1[25 + kh * 5 + kw], a1);
                    a2 = fmaf(xv, sw1[50 + kh * 5 + kw], a2);
                }
            v0 = fmaxf(a0, 0.f); v1 = fmaxf(a1, 0.f); v2 = fmaxf(a2, 0.f);
        }
        s1[0][rr][cc] = v0; s1[1][rr][cc] = v1; s1[2][rr][cc] = v2;
    }
    __syncthreads();
    // phase 2: conv2, all 5 channels per thread (shares the LDS window reads)
    int loh = tid >> 4, low = tid & 15;
    int oh = OH0 + loh, ow = OW0 + low;
    if (oh < C2N && ow < C2N) {
        float acc[5] = {b2[0], b2[1], b2[2], b2[3], b2[4]};
#pragma unroll
        for (int ci = 0; ci < 3; ++ci)
#pragma unroll
            for (int kh = 0; kh < 5; ++kh)
#pragma unroll
                for (int kw = 0; kw < 5; ++kw) {
                    float sv = s1[ci][2 * loh + kh][2 * low + kw];
                    int wof = ci * 25 + kh * 5 + kw;
#pragma unroll
                    for (int c = 0; c < 5; ++c)
                        acc[c] = fmaf(sv, sw2[c * 75 + wof], acc[c]);
                }
#pragma unroll
        for (int c = 0; c < 5; ++c)
            f0[c * (C2N * C2N) + oh * C2N + ow] = acc[c];
    }
}

// ---- Gp[s][c][p] partial: sum over hw-chunk s of f0[c,hw]*proj[hw,p] (c=5: f0==1) ----
// grid (6, PSPLIT)
__global__ __launch_bounds__(256) void k_proj(const float* __restrict__ f0,
        const float* __restrict__ proj, float* __restrict__ Gp) {
    int c = blockIdx.x, s = blockIdx.y, tid = threadIdx.x;
    const int HW = C2N * C2N;
    const int CH = (HW + PSPLIT - 1) / PSPLIT;   // 977
    int hw_end = min(HW, (s + 1) * CH);
    float acc[NP];
#pragma unroll
    for (int p = 0; p < NP; ++p) acc[p] = 0.0f;
    for (int hw = s * CH + tid; hw < hw_end; hw += 256) {
        float v = (c < 5) ? f0[c * HW + hw] : 1.0f;
        const float* pp = proj + (size_t)hw * NP;
#pragma unroll
        for (int p = 0; p < NP; ++p) acc[p] = fmaf(v, pp[p], acc[p]);
    }
    __shared__ float red[4][NP];
    int lane = tid & 63, wv = tid >> 6;
#pragma unroll
    for (int p = 0; p < NP; ++p) {
        float v = acc[p];
        for (int off = 32; off; off >>= 1) v += __shfl_xor(v, off, 64);
        if (lane == 0) red[wv][p] = v;
    }
    __syncthreads();
    if (tid < NP)
        Gp[(s * 6 + c) * NP + tid] = red[0][tid] + red[1][tid] + red[2][tid] + red[3][tid];
}

// ---- harm[o,m] = (1/sqrt(20)) * sum_p (sum_c p_w[o,c]G[c,p] + p_b[o]*G[5,p]) * Yp[p,m] ----
__global__ __launch_bounds__(256) void k_harm(const float* __restrict__ Gp,
        const float* __restrict__ p_w, const float* __restrict__ p_b,
        const float* __restrict__ Yp, float* __restrict__ harm) {
    __shared__ float sG[6 * NP];
    __shared__ float sY[NP * NH];
    int tid = threadIdx.x;
    if (tid < 6 * NP) {
        float a = 0.0f;
        for (int s = 0; s < PSPLIT; ++s) a += Gp[s * (6 * NP) + tid];
        sG[tid] = a;
    }
    for (int i = tid; i < NP * NH; i += 256) sY[i] = Yp[i];
    __syncthreads();
    int idx = blockIdx.x * 256 + tid;
    if (idx >= NSPH * NH) return;
    int o = idx / NH, m = idx - o * NH;
    float pb = p_b[o];
    const float* pw = p_w + o * 5;
    float acc = 0.0f;
#pragma unroll
    for (int p = 0; p < NP; ++p) {
        float pts = pb * sG[5 * NP + p];
#pragma unroll
        for (int cc = 0; cc < 5; ++cc) pts = fmaf(pw[cc], sG[cc * NP + p], pts);
        acc = fmaf(pts, sY[p * NH + m], acc);
    }
    harm[idx] = acc * (1.0f / 4.47213595499957939f); // 1/sqrt(20)
}

// ---- T[(m),(yn)] = sum_x s2_w[x,(yn)] * harm[x,m]; split-K over x (8 chunks of 64) ----
// atomic==0: plain stores to Tpart[(bidy*25+m)*YN + yn]; atomic==1: atomicAdd T[m*YN+yn]
#define XCH 64
__global__ __launch_bounds__(256) void k_T(const float* __restrict__ s2w,
        const float* __restrict__ harm, float* __restrict__ T, int atomic) {
    int yn = blockIdx.x * 256 + threadIdx.x;   // 0..12287
    int x0 = blockIdx.y * XCH;
    __shared__ float sh[XCH * NH];
    for (int i = threadIdx.x; i < XCH * NH; i += 256) sh[i] = harm[x0 * NH + i];
    __syncthreads();
    float acc[NH];
#pragma unroll
    for (int m = 0; m < NH; ++m) acc[m] = 0.0f;
    const float* ap = s2w + (size_t)x0 * YN + yn;
#pragma unroll 8
    for (int xi = 0; xi < XCH; ++xi) {
        float a = ap[(size_t)xi * YN];
        const float* hr = sh + xi * NH;
#pragma unroll
        for (int m = 0; m < NH; ++m) acc[m] = fmaf(a, hr[m], acc[m]);
    }
    if (atomic) {
#pragma unroll
        for (int m = 0; m < NH; ++m) atomicAdd(T + (size_t)m * YN + yn, acc[m]);
    } else {
        float* tp = T + (size_t)(blockIdx.y * NH) * YN + yn;
#pragma unroll
        for (int m = 0; m < NH; ++m) tp[(size_t)m * YN] = acc[m];
    }
}

// ---- fused per-y: sum T parts; h = S2conv irrep contraction; s = sqrt2*relu(h@Dact^T);
//      h2 = s@Dact/576 ----
__global__ __launch_bounds__(576) void k_so3block(const float* __restrict__ T,
        const float* __restrict__ Ys2, const float* __restrict__ Dact,
        float* __restrict__ h2, int nparts) {
    int y = blockIdx.x, tid = threadIdx.x;
    __shared__ float sY[NK * NH];   // 19.2 KB
    __shared__ float sT[NK * NH];   // 19.2 KB
    __shared__ float shh[NI];
    __shared__ float ss[NG];
    for (int i = tid; i < NK * NH; i += NG) sY[i] = Ys2[i];
    for (int j = tid; j < NK * NH; j += NG) {
        int m = j / NK, n = j - m * NK;
        float acc = 0.0f;
        const float* tp = T + (size_t)m * YN + y * NK + n;
        for (int p = 0; p < nparts; ++p) acc += tp[(size_t)p * NH * YN];
        sT[n * NH + m] = acc;
    }
    __syncthreads();
    if (tid < NI) {
        int l, o, d, u, m;
        decode_irr(tid, l, o, d, u, m);
        int cu = l * l + u, cm = l * l + m;
        float acc = 0.0f;
        for (int n = 0; n < NK; ++n)
            acc = fmaf(sY[n * NH + cu], sT[n * NH + cm], acc);
        shh[tid] = acc * (1.0f / 313.534098402587976f); // 1/sqrt(192*512)
    }
    __syncthreads();
    {   // s[g] for g = tid (all 576 threads)
        const float* dr = Dact + (size_t)tid * NI;
        float acc = 0.0f;
        for (int i = 0; i < NI; ++i) acc = fmaf(shh[i], dr[i], acc);
        ss[tid] = 1.41421356237309515f * fmaxf(acc, 0.0f);
    }
    __syncthreads();
    if (tid < NI) {
        float acc = 0.0f;
        for (int g = 0; g < NG; ++g) acc = fmaf(ss[g], Dact[(size_t)g * NI + tid], acc);
        h2[y * NI + tid] = acc * (1.0f / (float)NG);
    }
}

// ---- psi2[x,i] = (1/sqrt(192)) * sum_n so3_w[x,n] * D_so3k[n,i] ----
__global__ __launch_bounds__(192) void k_psi2(const float* __restrict__ w,
        const float* __restrict__ D, float* __restrict__ psi2) {
    __shared__ float sw[NK];
    int x = blockIdx.x, t = threadIdx.x;
    if (t < NK) sw[t] = w[x * NK + t];
    __syncthreads();
    if (t >= NI) return;
    float acc = 0.0f;
    for (int n = 0; n < NK; ++n) acc = fmaf(sw[n], D[(size_t)n * NI + t], acc);
    psi2[x * NI + t] = acc * (1.0f / 13.8564064605510175f); // 1/sqrt(192)
}

// ---- fused BN (training stats, in LDS) + SO3Conv + eval matmul + sigmoid ----
// grid 48, block 192; each block produces 96 outputs (BN/so3conv recomputed per block)
__global__ __launch_bounds__(192) void k_eval(const float* __restrict__ psi2,
        const float* __restrict__ h2, const float* __restrict__ gamma,
        const float* __restrict__ beta, const float* __restrict__ ew,
        float* __restrict__ out) {
    __shared__ float sp[NY * NI];   // 42.24 KB
    __shared__ float sh[NY * NI];   // 42.24 KB
    __shared__ float sho[NI];
    int tid = threadIdx.x;
    for (int i = tid; i < NY * NI; i += 192) { sp[i] = psi2[i]; sh[i] = h2[i]; }
    __syncthreads();
    if (tid < NI) {   // BatchNorm over the 64 rows of column tid, in LDS
        float s = 0.0f;
        for (int f = 0; f < NY; ++f) s += sh[f * NI + tid];
        float mu = s * (1.0f / NY);
        float v = 0.0f;
        for (int f = 0; f < NY; ++f) { float d = sh[f * NI + tid] - mu; v = fmaf(d, d, v); }
        float sc = rsqrtf(v * (1.0f / NY) + 1e-5f) * gamma[tid];
        float bt = beta[tid];
        for (int f = 0; f < NY; ++f) sh[f * NI + tid] = (sh[f * NI + tid] - mu) * sc + bt;
    }
    __syncthreads();
    if (tid < NI) {   // SO3Convolution -> sho
        int l, o, d, u, m;
        decode_irr(tid, l, o, d, u, m);
        // 1/sqrt(64*d) for d = 1,3,5,7,9
        const float invsc[5] = {0.125f, 0.0721687836487032f, 0.0559016994374947f,
                                0.0472455591261534f, 0.0416666666666667f};
        float acc = 0.0f;
        for (int x = 0; x < NY; ++x) {
            const float* pr = sp + x * NI + o;
            const float* hr = sh + x * NI + o;
            for (int v = 0; v < d; ++v) acc = fmaf(pr[u * d + v], hr[v * d + m], acc);
        }
        sho[tid] = acc * invsc[l];
    }
    __syncthreads();
    if (tid < 96) {
        int g = blockIdx.x * 96 + tid;
        float acc = 0.0f;
        for (int i = 0; i < NI; ++i) acc = fmaf(sho[i], ew[(size_t)i * NE + g], acc);
        out[g] = 1.0f / (1.0f + expf(-acc));
    }
}

extern "C" void kernel_launch(void* const* d_in, const int* in_sizes, int n_in,
                              void* d_out, int out_size, void* d_ws, size_t ws_size,
                              hipStream_t stream) {
    const float* x      = (const float*)d_in[0];
    const float* c1w    = (const float*)d_in[1];
    const float* c1b    = (const float*)d_in[2];
    const float* c2w    = (const float*)d_in[3];
    const float* c2b    = (const float*)d_in[4];
    const float* p_w    = (const float*)d_in[5];
    const float* p_b    = (const float*)d_in[6];
    const float* projw  = (const float*)d_in[7];
    const float* Yp     = (const float*)d_in[8];
    const float* s2w    = (const float*)d_in[9];
    const float* Ys2    = (const float*)d_in[10];
    const float* gamma  = (const float*)d_in[11];
    const float* beta   = (const float*)d_in[12];
    const float* so3w   = (const float*)d_in[13];
    const float* Dso3k  = (const float*)d_in[14];
    const float* Dact   = (const float*)d_in[15];
    const float* ew     = (const float*)d_in[16];
    float* out = (float*)d_out;

    float* ws   = (float*)d_ws;
    float* f0   = ws;                  // 5*15625 = 78125 -> pad 78128
    float* Gp   = f0 + 78128;          // 16*120 = 1920
    float* harm = Gp + 1920;           // 512*25 = 12800
    float* h2   = harm + 12800;        // 64*165 = 10560
    float* psi2 = h2 + 10560;          // 10560
    float* T    = psi2 + 10560;        // nparts*307200

    // choose split-K strategy by available scratch (constant per process -> graph-safe)
    const size_t base = 78128 + 1920 + 12800 + 10560 + 10560;
    bool big = ws_size >= (base + 8u * 307200u) * sizeof(float);
    int nparts = big ? 8 : 1;
    if (!big) hipMemsetAsync(T, 0, (size_t)307200 * sizeof(float), stream);

    k_conv<<<dim3(8, 8), 256, 0, stream>>>(x, c1w, c1b, c2w, c2b, f0);
    k_proj<<<dim3(6, PSPLIT), 256, 0, stream>>>(f0, projw, Gp);
    k_harm<<<(NSPH * NH + 255) / 256, 256, 0, stream>>>(Gp, p_w, p_b, Yp, harm);
    k_T<<<dim3(48, 8), 256, 0, stream>>>(s2w, harm, T, big ? 0 : 1);
    k_so3block<<<NY, NG, 0, stream>>>(T, Ys2, Dact, h2, nparts);
    k_psi2<<<NY, 192, 0, stream>>>(so3w, Dso3k, psi2);
    k_eval<<<48, 192, 0, stream>>>(psi2, h2, gamma, beta, ew, out);
}

// Round 4
// 242.669 us; speedup vs baseline: 1.0284x; 1.0284x over previous
//
#include <hip/hip_runtime.h>
#include <math.h>

#define IMG 509
#define C1N 253
#define C2N 125
#define NSPH 512   // SPHERE_FDIM
#define NY 64      // SO3_F1
#define NK 192     // kernel-grid points
#define NH 25      // (LMAX+1)^2
#define NI 165     // sum (2l+1)^2
#define NG 576     // activation grid
#define NE 4608    // eval grid
#define NP 20      // projector points
#define YN 12288   // NY*NK
#define PSPLIT 16  // k_proj hw splits

// decode flat irrep index t in [0,165) -> (l, offset, d, row u, col m)
__device__ __forceinline__ void decode_irr(int t, int& l, int& o, int& d, int& u, int& m) {
    if (t < 1)       { l = 0; o = 0;  }
    else if (t < 10) { l = 1; o = 1;  }
    else if (t < 35) { l = 2; o = 10; }
    else if (t < 84) { l = 3; o = 35; }
    else             { l = 4; o = 84; }
    d = 2 * l + 1;
    int r = t - o;
    u = r / d;
    m = r - u * d;
}

// ---- fused conv1(stride2)+relu+conv2(stride2), batch sample 0 only ----
__global__ __launch_bounds__(256) void k_conv(const float* __restrict__ x,
        const float* __restrict__ w1, const float* __restrict__ b1,
        const float* __restrict__ w2, const float* __restrict__ b2,
        float* __restrict__ f0) {
    __shared__ float s1[3][35][36];   // +1 pad
    __shared__ float sw1[75];
    __shared__ float sw2[375];
    int tid = threadIdx.x;
    if (tid < 75) sw1[tid] = w1[tid];
    for (int j = tid; j < 375; j += 256) sw2[j] = w2[j];
    int OH0 = blockIdx.y * 16, OW0 = blockIdx.x * 16;
    int R0 = 2 * OH0, C0 = 2 * OW0;
    float bb0 = b1[0], bb1 = b1[1], bb2 = b1[2];
    __syncthreads();
    for (int j = tid; j < 35 * 35; j += 256) {
        int rr = j / 35, cc = j - rr * 35;
        int r = R0 + rr, c = C0 + cc;
        float v0 = 0.f, v1 = 0.f, v2 = 0.f;
        if (r < C1N && c < C1N) {
            const float* xp = x + (2 * r) * IMG + 2 * c;
            float a0 = bb0, a1 = bb1, a2 = bb2;
#pragma unroll
            for (int kh = 0; kh < 5; ++kh)
#pragma unroll
                for (int kw = 0; kw < 5; ++kw) {
                    float xv = xp[kh * IMG + kw];
                    a0 = fmaf(xv, sw1[kh * 5 + kw], a0);
                    a1 = fmaf(xv, sw1[25 + kh * 5 + kw], a1);
                    a2 = fmaf(xv, sw1[50 + kh * 5 + kw], a2);
                }
            v0 = fmaxf(a0, 0.f); v1 = fmaxf(a1, 0.f); v2 = fmaxf(a2, 0.f);
        }
        s1[0][rr][cc] = v0; s1[1][rr][cc] = v1; s1[2][rr][cc] = v2;
    }
    __syncthreads();
    int loh = tid >> 4, low = tid & 15;
    int oh = OH0 + loh, ow = OW0 + low;
    if (oh < C2N && ow < C2N) {
        float acc[5] = {b2[0], b2[1], b2[2], b2[3], b2[4]};
#pragma unroll
        for (int ci = 0; ci < 3; ++ci)
#pragma unroll
            for (int kh = 0; kh < 5; ++kh)
#pragma unroll
                for (int kw = 0; kw < 5; ++kw) {
                    float sv = s1[ci][2 * loh + kh][2 * low + kw];
                    int wof = ci * 25 + kh * 5 + kw;
#pragma unroll
                    for (int c = 0; c < 5; ++c)
                        acc[c] = fmaf(sv, sw2[c * 75 + wof], acc[c]);
                }
#pragma unroll
        for (int c = 0; c < 5; ++c)
            f0[c * (C2N * C2N) + oh * C2N + ow] = acc[c];
    }
}

// ---- Gp[s][c][p] partials ----
__global__ __launch_bounds__(256) void k_proj(const float* __restrict__ f0,
        const float* __restrict__ proj, float* __restrict__ Gp) {
    int c = blockIdx.x, s = blockIdx.y, tid = threadIdx.x;
    const int HW = C2N * C2N;
    const int CH = (HW + PSPLIT - 1) / PSPLIT;   // 977
    int hw_end = min(HW, (s + 1) * CH);
    float acc[NP];
#pragma unroll
    for (int p = 0; p < NP; ++p) acc[p] = 0.0f;
    for (int hw = s * CH + tid; hw < hw_end; hw += 256) {
        float v = (c < 5) ? f0[c * HW + hw] : 1.0f;
        const float* pp = proj + (size_t)hw * NP;
#pragma unroll
        for (int p = 0; p < NP; ++p) acc[p] = fmaf(v, pp[p], acc[p]);
    }
    __shared__ float red[4][NP];
    int lane = tid & 63, wv = tid >> 6;
#pragma unroll
    for (int p = 0; p < NP; ++p) {
        float v = acc[p];
        for (int off = 32; off; off >>= 1) v += __shfl_xor(v, off, 64);
        if (lane == 0) red[wv][p] = v;
    }
    __syncthreads();
    if (tid < NP)
        Gp[(s * 6 + c) * NP + tid] = red[0][tid] + red[1][tid] + red[2][tid] + red[3][tid];
}

// ---- harm[o,m] ----
__global__ __launch_bounds__(256) void k_harm(const float* __restrict__ Gp,
        const float* __restrict__ p_w, const float* __restrict__ p_b,
        const float* __restrict__ Yp, float* __restrict__ harm) {
    __shared__ float sG[6 * NP];
    __shared__ float sY[NP * NH];
    int tid = threadIdx.x;
    if (tid < 6 * NP) {
        float a = 0.0f;
        for (int s = 0; s < PSPLIT; ++s) a += Gp[s * (6 * NP) + tid];
        sG[tid] = a;
    }
    for (int i = tid; i < NP * NH; i += 256) sY[i] = Yp[i];
    __syncthreads();
    int idx = blockIdx.x * 256 + tid;
    if (idx >= NSPH * NH) return;
    int o = idx / NH, m = idx - o * NH;
    float pb = p_b[o];
    const float* pw = p_w + o * 5;
    float acc = 0.0f;
#pragma unroll
    for (int p = 0; p < NP; ++p) {
        float pts = pb * sG[5 * NP + p];
#pragma unroll
        for (int cc = 0; cc < 5; ++cc) pts = fmaf(pw[cc], sG[cc * NP + p], pts);
        acc = fmaf(pts, sY[p * NH + m], acc);
    }
    harm[idx] = acc * (1.0f / 4.47213595499957939f); // 1/sqrt(20)
}

// ---- DactT[i*576+g] = Dact[g*165+i] ----
__global__ __launch_bounds__(256) void k_trans(const float* __restrict__ D,
        float* __restrict__ DT) {
    int j = blockIdx.x * 256 + threadIdx.x;
    if (j >= NG * NI) return;
    int g = j / NI, i = j - g * NI;
    DT[(size_t)i * NG + g] = D[j];
}

// ---- T[(m),(yn)] split-K over x ----
#define XCH 64
__global__ __launch_bounds__(256) void k_T(const float* __restrict__ s2w,
        const float* __restrict__ harm, float* __restrict__ T, int atomic) {
    int yn = blockIdx.x * 256 + threadIdx.x;   // 0..12287
    int x0 = blockIdx.y * XCH;
    __shared__ float sh[XCH * NH];
    for (int i = threadIdx.x; i < XCH * NH; i += 256) sh[i] = harm[x0 * NH + i];
    __syncthreads();
    float acc[NH];
#pragma unroll
    for (int m = 0; m < NH; ++m) acc[m] = 0.0f;
    const float* ap = s2w + (size_t)x0 * YN + yn;
#pragma unroll 8
    for (int xi = 0; xi < XCH; ++xi) {
        float a = ap[(size_t)xi * YN];
        const float* hr = sh + xi * NH;
#pragma unroll
        for (int m = 0; m < NH; ++m) acc[m] = fmaf(a, hr[m], acc[m]);
    }
    if (atomic) {
#pragma unroll
        for (int m = 0; m < NH; ++m) atomicAdd(T + (size_t)m * YN + yn, acc[m]);
    } else {
        float* tp = T + (size_t)(blockIdx.y * NH) * YN + yn;
#pragma unroll
        for (int m = 0; m < NH; ++m) tp[(size_t)m * YN] = acc[m];
    }
}

// ---- fused per-y: sum T parts; h; s = sqrt2*relu(h@DactT); h2 = s@Dact/576 ----
__global__ __launch_bounds__(576) void k_so3block(const float* __restrict__ T,
        const float* __restrict__ Ys2, const float* __restrict__ Dact,
        const float* __restrict__ DactT, float* __restrict__ h2, int nparts) {
    int y = blockIdx.x, tid = threadIdx.x;
    __shared__ float sY[NK * NH];   // 19.2 KB
    __shared__ float sT[NK * NH];   // 19.2 KB
    __shared__ float shh[NI];
    __shared__ float ss[NG];
    for (int i = tid; i < NK * NH; i += NG) sY[i] = Ys2[i];
    for (int j = tid; j < NK * NH; j += NG) {
        int m = j / NK, n = j - m * NK;
        float acc = 0.0f;
        const float* tp = T + (size_t)m * YN + y * NK + n;
        for (int p = 0; p < nparts; ++p) acc += tp[(size_t)p * NH * YN];
        sT[n * NH + m] = acc;
    }
    __syncthreads();
    if (tid < NI) {
        int l, o, d, u, m;
        decode_irr(tid, l, o, d, u, m);
        int cu = l * l + u, cm = l * l + m;
        float acc = 0.0f;
        for (int n = 0; n < NK; ++n)
            acc = fmaf(sY[n * NH + cu], sT[n * NH + cm], acc);
        shh[tid] = acc * (1.0f / 313.534098402587976f); // 1/sqrt(192*512)
    }
    __syncthreads();
    {   // s[g], g = tid; coalesced DactT reads
        float acc = 0.0f;
        for (int i = 0; i < NI; ++i)
            acc = fmaf(shh[i], DactT[(size_t)i * NG + tid], acc);
        ss[tid] = 1.41421356237309515f * fmaxf(acc, 0.0f);
    }
    __syncthreads();
    if (tid < NI) {
        float acc = 0.0f;
        for (int g = 0; g < NG; ++g) acc = fmaf(ss[g], Dact[(size_t)g * NI + tid], acc);
        h2[y * NI + tid] = acc * (1.0f / (float)NG);
    }
}

// ---- psi2[x,i] ----
__global__ __launch_bounds__(192) void k_psi2(const float* __restrict__ w,
        const float* __restrict__ D, float* __restrict__ psi2) {
    __shared__ float sw[NK];
    int x = blockIdx.x, t = threadIdx.x;
    if (t < NK) sw[t] = w[x * NK + t];
    __syncthreads();
    if (t >= NI) return;
    float acc = 0.0f;
    for (int n = 0; n < NK; ++n) acc = fmaf(sw[n], D[(size_t)n * NI + t], acc);
    psi2[x * NI + t] = acc * (1.0f / 13.8564064605510175f); // 1/sqrt(192)
}

// ---- BN (training stats) + SO3Conv, one block per l ----
__global__ __launch_bounds__(256) void k_bnso3(const float* __restrict__ psi2,
        const float* __restrict__ h2, const float* __restrict__ gamma,
        const float* __restrict__ beta, float* __restrict__ ho) {
    __shared__ float sp[NY * 81];   // 20.7 KB
    __shared__ float sh[NY * 81];   // 20.7 KB
    __shared__ float sred[81];
    const int OFF[5] = {0, 1, 10, 35, 84};
    const float invsc[5] = {0.125f, 0.0721687836487032f, 0.0559016994374947f,
                            0.0472455591261534f, 0.0416666666666667f};
    int l = blockIdx.x;
    int o = OFF[l], d = 2 * l + 1, d2 = d * d;
    int tid = threadIdx.x;
    int n = NY * d2;
    for (int k = tid; k < n; k += 256) {
        int x = k / d2, j = k - x * d2;
        sp[k] = psi2[x * NI + o + j];
        sh[k] = h2[x * NI + o + j];
    }
    __syncthreads();
    if (tid < d2) {   // BN column o+tid over 64 rows
        float s = 0.0f;
        for (int x = 0; x < NY; ++x) s += sh[x * d2 + tid];
        float mu = s * (1.0f / NY);
        float v = 0.0f;
        for (int x = 0; x < NY; ++x) { float df = sh[x * d2 + tid] - mu; v = fmaf(df, df, v); }
        float sc = rsqrtf(v * (1.0f / NY) + 1e-5f) * gamma[o + tid];
        float bt = beta[o + tid];
        for (int x = 0; x < NY; ++x) sh[x * d2 + tid] = (sh[x * d2 + tid] - mu) * sc + bt;
    }
    __syncthreads();
    int half = tid / d2;
    int j = tid - half * d2;
    float acc = 0.0f;
    if (half < 2) {
        int u = j / d, m = j - u * d;
        for (int x = half * 32; x < half * 32 + 32; ++x) {
            const float* pr = sp + x * d2 + u * d;
            const float* hr = sh + x * d2 + m;
            for (int v = 0; v < d; ++v) acc = fmaf(pr[v], hr[v * d], acc);
        }
        if (half == 1) sred[j] = acc;
    }
    __syncthreads();
    if (tid < d2)
        ho[o + tid] = (acc + sred[tid]) * invsc[l];
}

// ---- partial logits: lp[q,g] = sum_{i in quarter q} ho[i]*ew[i,g] ----
__global__ __launch_bounds__(256) void k_out(const float* __restrict__ ho,
        const float* __restrict__ ew, float* __restrict__ lp) {
    __shared__ float sho[NI];
    int tid = threadIdx.x;
    if (tid < NI) sho[tid] = ho[tid];
    __syncthreads();
    int g = blockIdx.x * 256 + tid;
    int q = blockIdx.y;
    int i0 = q * 42, i1 = min(NI, i0 + 42);
    float acc = 0.0f;
    for (int i = i0; i < i1; ++i) acc = fmaf(sho[i], ew[(size_t)i * NE + g], acc);
    lp[(size_t)q * NE + g] = acc;
}

// ---- out[g] = sigmoid(sum_q lp[q,g]) ----
__global__ __launch_bounds__(256) void k_sig(const float* __restrict__ lp,
        float* __restrict__ out) {
    int g = blockIdx.x * 256 + threadIdx.x;
    float a = lp[g] + lp[NE + g] + lp[2 * NE + g] + lp[3 * NE + g];
    out[g] = 1.0f / (1.0f + expf(-a));
}

extern "C" void kernel_launch(void* const* d_in, const int* in_sizes, int n_in,
                              void* d_out, int out_size, void* d_ws, size_t ws_size,
                              hipStream_t stream) {
    const float* x      = (const float*)d_in[0];
    const float* c1w    = (const float*)d_in[1];
    const float* c1b    = (const float*)d_in[2];
    const float* c2w    = (const float*)d_in[3];
    const float* c2b    = (const float*)d_in[4];
    const float* p_w    = (const float*)d_in[5];
    const float* p_b    = (const float*)d_in[6];
    const float* projw  = (const float*)d_in[7];
    const float* Yp     = (const float*)d_in[8];
    const float* s2w    = (const float*)d_in[9];
    const float* Ys2    = (const float*)d_in[10];
    const float* gamma  = (const float*)d_in[11];
    const float* beta   = (const float*)d_in[12];
    const float* so3w   = (const float*)d_in[13];
    const float* Dso3k  = (const float*)d_in[14];
    const float* Dact   = (const float*)d_in[15];
    const float* ew     = (const float*)d_in[16];
    float* out = (float*)d_out;

    float* ws    = (float*)d_ws;
    float* f0    = ws;                  // 78128
    float* Gp    = f0 + 78128;          // 1920
    float* harm  = Gp + 1920;           // 12800
    float* h2    = harm + 12800;        // 10560
    float* psi2  = h2 + 10560;          // 10560
    float* ho    = psi2 + 10560;        // 192
    float* DactT = ho + 192;            // 95040
    float* lp    = DactT + 95040;       // 4*4608 = 18432
    float* T     = lp + 18432;          // nparts*307200

    const size_t base = 78128 + 1920 + 12800 + 10560 + 10560 + 192 + 95040 + 18432;
    bool big = ws_size >= (base + 8u * 307200u) * sizeof(float);
    int nparts = big ? 8 : 1;
    if (!big) hipMemsetAsync(T, 0, (size_t)307200 * sizeof(float), stream);

    k_conv<<<dim3(8, 8), 256, 0, stream>>>(x, c1w, c1b, c2w, c2b, f0);
    k_trans<<<(NG * NI + 255) / 256, 256, 0, stream>>>(Dact, DactT);
    k_proj<<<dim3(6, PSPLIT), 256, 0, stream>>>(f0, projw, Gp);
    k_harm<<<(NSPH * NH + 255) / 256, 256, 0, stream>>>(Gp, p_w, p_b, Yp, harm);
    k_T<<<dim3(48, 8), 256, 0, stream>>>(s2w, harm, T, big ? 0 : 1);
    k_so3block<<<NY, NG, 0, stream>>>(T, Ys2, Dact, DactT, h2, nparts);
    k_psi2<<<NY, 192, 0, stream>>>(so3w, Dso3k, psi2);
    k_bnso3<<<5, 256, 0, stream>>>(psi2, h2, gamma, beta, ho);
    k_out<<<dim3(18, 4), 256, 0, stream>>>(ho, ew, lp);
    k_sig<<<18, 256, 0, stream>>>(lp, out);
}

// Round 9
// 225.895 us; speedup vs baseline: 1.1048x; 1.0743x over previous
//
#include <hip/hip_runtime.h>
#include <math.h>

#define IMG 509
#define C1N 253
#define C2N 125
#define NSPH 512   // SPHERE_FDIM
#define NY 64      // SO3_F1
#define NK 192     // kernel-grid points
#define NH 25      // (LMAX+1)^2
#define NI 165     // sum (2l+1)^2
#define NG 576     // activation grid
#define NE 4608    // eval grid
#define NP 20      // projector points
#define YN 12288   // NY*NK

// decode flat irrep index t in [0,165) -> (l, offset, d, row u, col m)
__device__ __forceinline__ void decode_irr(int t, int& l, int& o, int& d, int& u, int& m) {
    if (t < 1)       { l = 0; o = 0;  }
    else if (t < 10) { l = 1; o = 1;  }
    else if (t < 35) { l = 2; o = 10; }
    else if (t < 84) { l = 3; o = 35; }
    else             { l = 4; o = 84; }
    d = 2 * l + 1;
    int r = t - o;
    u = r / d;
    m = r - u * d;
}

// ============ k_pre: block-packed independent work ============
// blocks [0,150):   proj partials Gp[s][c][p], c=b/25 (c==5 -> ones row), s=b%25
//                   (conv1+relu+conv2 inlined for the 5-row chunk; f0 never materialized)
// blocks [150,522): DactT[i*576+g] = Dact[g*165+i]
// blocks [522,586): psi2[x,:] = so3w[x,:] @ Dso3k / sqrt(192)
// blocks [586,886): zero T (float4)
__global__ __launch_bounds__(256) void k_pre(const float* __restrict__ x,
        const float* __restrict__ w1, const float* __restrict__ b1,
        const float* __restrict__ w2, const float* __restrict__ b2,
        const float* __restrict__ projw,
        const float* __restrict__ Dact, float* __restrict__ DactT,
        const float* __restrict__ so3w, const float* __restrict__ Dso3k,
        float* __restrict__ psi2, float* __restrict__ Gp, float* __restrict__ T) {
    __shared__ float s1[3 * 13 * 254];   // 39.6 KB conv1 tile (rows padded to 254)
    __shared__ float sw1[75];
    __shared__ float sw2[75];
    __shared__ float red[4][NP];
    int b = blockIdx.x, tid = threadIdx.x;
    if (b < 150) {
        int c = b / 25, s = b - 25 * c;
        float acc[NP];
#pragma unroll
        for (int p = 0; p < NP; ++p) acc[p] = 0.0f;
        if (c < 5) {
            if (tid < 75) { sw1[tid] = w1[tid]; sw2[tid] = w2[c * 75 + tid]; }
            __syncthreads();
            float bb0 = b1[0], bb1 = b1[1], bb2 = b1[2];
            // conv1 rows q in [10s, 10s+13), cols 0..252, 3 channels
            for (int j = tid; j < 13 * 253; j += 256) {
                int lq = j / 253, col = j - lq * 253;
                int q = 10 * s + lq;
                const float* xp = x + (2 * q) * IMG + 2 * col;
                float a0 = bb0, a1 = bb1, a2 = bb2;
#pragma unroll
                for (int kh = 0; kh < 5; ++kh)
#pragma unroll
                    for (int kw = 0; kw < 5; ++kw) {
                        float xv = xp[kh * IMG + kw];
                        a0 = fmaf(xv, sw1[kh * 5 + kw], a0);
                        a1 = fmaf(xv, sw1[25 + kh * 5 + kw], a1);
                        a2 = fmaf(xv, sw1[50 + kh * 5 + kw], a2);
                    }
                s1[lq * 254 + col] = fmaxf(a0, 0.f);
                s1[13 * 254 + lq * 254 + col] = fmaxf(a1, 0.f);
                s1[2 * 13 * 254 + lq * 254 + col] = fmaxf(a2, 0.f);
            }
            __syncthreads();
            float b2c = b2[c];
            // conv2 rows oh in [5s,5s+5) + proj accumulate
            for (int j = tid; j < 625; j += 256) {
                int lr = j / 125, ow = j - lr * 125;
                float v = b2c;
#pragma unroll
                for (int ci = 0; ci < 3; ++ci)
#pragma unroll
                    for (int kh = 0; kh < 5; ++kh)
#pragma unroll
                        for (int kw = 0; kw < 5; ++kw)
                            v = fmaf(s1[ci * (13 * 254) + (2 * lr + kh) * 254 + 2 * ow + kw],
                                     sw2[ci * 25 + kh * 5 + kw], v);
                const float* pp = projw + (size_t)(625 * s + j) * NP;
#pragma unroll
                for (int p = 0; p < NP; ++p) acc[p] = fmaf(v, pp[p], acc[p]);
            }
        } else {
            for (int j = tid; j < 625; j += 256) {
                const float* pp = projw + (size_t)(625 * s + j) * NP;
#pragma unroll
                for (int p = 0; p < NP; ++p) acc[p] += pp[p];
            }
        }
        int lane = tid & 63, wv = tid >> 6;
#pragma unroll
        for (int p = 0; p < NP; ++p) {
            float v = acc[p];
            for (int off = 32; off; off >>= 1) v += __shfl_xor(v, off, 64);
            if (lane == 0) red[wv][p] = v;
        }
        __syncthreads();
        if (tid < NP)
            Gp[(s * 6 + c) * NP + tid] = red[0][tid] + red[1][tid] + red[2][tid] + red[3][tid];
    } else if (b < 522) {
        int j = (b - 150) * 256 + tid;
        if (j < NG * NI) {
            int g = j / NI, i = j - g * NI;
            DactT[(size_t)i * NG + g] = Dact[j];
        }
    } else if (b < 586) {
        __shared__ float sw[NK];
        int xx = b - 522;
        if (tid < NK) sw[tid] = so3w[xx * NK + tid];
        __syncthreads();
        if (tid < NI) {
            float a = 0.0f;
            for (int n = 0; n < NK; ++n) a = fmaf(sw[n], Dso3k[(size_t)n * NI + tid], a);
            psi2[xx * NI + tid] = a * (1.0f / 13.8564064605510175f); // 1/sqrt(192)
        }
    } else {
        int j = ((b - 586) * 256 + tid) * 4;
        if (j < NH * YN) {
            float4 z = {0.f, 0.f, 0.f, 0.f};
            *(float4*)(T + j) = z;
        }
    }
}

// ============ k_T2: T[m,yn] += (1/sqrt20) * sum_c W2part[yn,c] * M[c,m] ============
// G = sum_s Gp; M[c,m] = sum_p G[c,p]*Yp[p,m] (c=5 is the bias/ones row);
// W2part over this block's 64-x chunk; split-K over x via atomics.
__global__ __launch_bounds__(256) void k_T2(const float* __restrict__ s2w,
        const float* __restrict__ Gp, const float* __restrict__ Yp,
        const float* __restrict__ p_w, const float* __restrict__ p_b,
        float* __restrict__ T) {
    __shared__ float sG[120];
    __shared__ float sM[150];
    __shared__ float spw[320];
    __shared__ float spb[64];
    int tid = threadIdx.x;
    if (tid < 120) {
        float a = 0.0f;
        for (int s = 0; s < 25; ++s) a += Gp[s * 120 + tid];
        sG[tid] = a;
    }
    int x0 = blockIdx.y * 64;
    // FIX (r7 bug): block has 256 threads; previous code assumed 512 and left
    // spw[128:320) and ALL of spb uninitialized -> absmax 0.5 failure.
    for (int i = tid; i < 320; i += 256) spw[i] = p_w[x0 * 5 + i];
    if (tid < 64) spb[tid] = p_b[x0 + tid];
    __syncthreads();
    if (tid < 150) {
        int c = tid / 25, m = tid - 25 * c;
        float a = 0.0f;
#pragma unroll
        for (int p = 0; p < NP; ++p) a = fmaf(sG[c * NP + p], Yp[p * NH + m], a);
        sM[tid] = a * 0.22360679774997896f;   // fold 1/sqrt(20)
    }
    __syncthreads();
    int yn = blockIdx.x * 256 + tid;
    float w0 = 0.f, w1v = 0.f, w2v = 0.f, w3 = 0.f, w4 = 0.f, wb = 0.f;
    const float* ap = s2w + (size_t)x0 * YN + yn;
#pragma unroll 8
    for (int xi = 0; xi < 64; ++xi) {
        float a = ap[(size_t)xi * YN];
        w0 = fmaf(a, spw[xi * 5 + 0], w0);
        w1v = fmaf(a, spw[xi * 5 + 1], w1v);
        w2v = fmaf(a, spw[xi * 5 + 2], w2v);
        w3 = fmaf(a, spw[xi * 5 + 3], w3);
        w4 = fmaf(a, spw[xi * 5 + 4], w4);
        wb = fmaf(a, spb[xi], wb);
    }
#pragma unroll
    for (int m = 0; m < NH; ++m) {
        float v = wb * sM[125 + m];
        v = fmaf(w0, sM[m], v);
        v = fmaf(w1v, sM[25 + m], v);
        v = fmaf(w2v, sM[50 + m], v);
        v = fmaf(w3, sM[75 + m], v);
        v = fmaf(w4, sM[100 + m], v);
        atomicAdd(T + (size_t)m * YN + yn, v);
    }
}

// ============ k_so3block: per-y S2conv irreps -> act grid relu -> back ============
__global__ __launch_bounds__(576) void k_so3block(const float* __restrict__ T,
        const float* __restrict__ Ys2, const float* __restrict__ Dact,
        const float* __restrict__ DactT, float* __restrict__ h2) {
    int y = blockIdx.x, tid = threadIdx.x;
    __shared__ float sY[NK * NH];   // 19.2 KB
    __shared__ float sT[NK * NH];   // 19.2 KB
    __shared__ float shh[NI];
    __shared__ float ss[NG];
    for (int i = tid; i < NK * NH; i += NG) sY[i] = Ys2[i];
    for (int j = tid; j < NK * NH; j += NG) {
        int m = j / NK, n = j - m * NK;
        sT[n * NH + m] = T[(size_t)m * YN + y * NK + n];
    }
    __syncthreads();
    if (tid < NI) {
        int l, o, d, u, m;
        decode_irr(tid, l, o, d, u, m);
        int cu = l * l + u, cm = l * l + m;
        float acc = 0.0f;
        for (int n = 0; n < NK; ++n)
            acc = fmaf(sY[n * NH + cu], sT[n * NH + cm], acc);
        shh[tid] = acc * (1.0f / 313.534098402587976f); // 1/sqrt(192*512)
    }
    __syncthreads();
    {   // s[g], g = tid; coalesced DactT reads
        float acc = 0.0f;
        for (int i = 0; i < NI; ++i)
            acc = fmaf(shh[i], DactT[(size_t)i * NG + tid], acc);
        ss[tid] = 1.41421356237309515f * fmaxf(acc, 0.0f);
    }
    __syncthreads();
    if (tid < NI) {
        float acc = 0.0f;
        for (int g = 0; g < NG; ++g) acc = fmaf(ss[g], Dact[(size_t)g * NI + tid], acc);
        h2[y * NI + tid] = acc * (1.0f / (float)NG);
    }
}

// ============ k_final: BN (train stats) + SO3Conv + eval matmul + sigmoid ============
// grid 72 x 256; each block recomputes BN+so3conv from L2-resident psi2/h2 (cheap),
// then 64 outputs/block with 4-way i-split for ILP.
__global__ __launch_bounds__(256) void k_final(const float* __restrict__ psi2,
        const float* __restrict__ h2, const float* __restrict__ gamma,
        const float* __restrict__ beta, const float* __restrict__ ew,
        float* __restrict__ out) {
    __shared__ float sp[NY * NI];   // 42.24 KB
    __shared__ float sh[NY * NI];   // 42.24 KB
    __shared__ float sho[NI];
    __shared__ float sred[256];
    int tid = threadIdx.x;
    for (int i = tid; i < NY * NI; i += 256) { sp[i] = psi2[i]; sh[i] = h2[i]; }
    __syncthreads();
    if (tid < NI) {   // BatchNorm column tid over 64 rows
        float s = 0.0f;
        for (int f = 0; f < NY; ++f) s += sh[f * NI + tid];
        float mu = s * (1.0f / NY);
        float v = 0.0f;
        for (int f = 0; f < NY; ++f) { float d = sh[f * NI + tid] - mu; v = fmaf(d, d, v); }
        float sc = rsqrtf(v * (1.0f / NY) + 1e-5f) * gamma[tid];
        float bt = beta[tid];
        for (int f = 0; f < NY; ++f) sh[f * NI + tid] = (sh[f * NI + tid] - mu) * sc + bt;
    }
    __syncthreads();
    if (tid < NI) {   // SO3Convolution
        int l, o, d, u, m;
        decode_irr(tid, l, o, d, u, m);
        const float invsc[5] = {0.125f, 0.0721687836487032f, 0.0559016994374947f,
                                0.0472455591261534f, 0.0416666666666667f};
        float acc = 0.0f;
        for (int xx = 0; xx < NY; ++xx) {
            const float* pr = sp + xx * NI + o + u * d;
            const float* hr = sh + xx * NI + o + m;
            for (int v = 0; v < d; ++v) acc = fmaf(pr[v], hr[v * d], acc);
        }
        sho[tid] = acc * invsc[l];
    }
    __syncthreads();
    int iq = tid >> 6, gl = tid & 63;
    int g = blockIdx.x * 64 + gl;
    int i0 = iq * 42, i1 = min(NI, i0 + 42);
    float a = 0.0f;
    for (int i = i0; i < i1; ++i) a = fmaf(sho[i], ew[(size_t)i * NE + g], a);
    sred[tid] = a;
    __syncthreads();
    if (tid < 64) {
        float v = sred[tid] + sred[64 + tid] + sred[128 + tid] + sred[192 + tid];
        out[blockIdx.x * 64 + tid] = 1.0f / (1.0f + expf(-v));
    }
}

extern "C" void kernel_launch(void* const* d_in, const int* in_sizes, int n_in,
                              void* d_out, int out_size, void* d_ws, size_t ws_size,
                              hipStream_t stream) {
    const float* x      = (const float*)d_in[0];
    const float* c1w    = (const float*)d_in[1];
    const float* c1b    = (const float*)d_in[2];
    const float* c2w    = (const float*)d_in[3];
    const float* c2b    = (const float*)d_in[4];
    const float* p_w    = (const float*)d_in[5];
    const float* p_b    = (const float*)d_in[6];
    const float* projw  = (const float*)d_in[7];
    const float* Yp     = (const float*)d_in[8];
    const float* s2w    = (const float*)d_in[9];
    const float* Ys2    = (const float*)d_in[10];
    const float* gamma  = (const float*)d_in[11];
    const float* beta   = (const float*)d_in[12];
    const float* so3w   = (const float*)d_in[13];
    const float* Dso3k  = (const float*)d_in[14];
    const float* Dact   = (const float*)d_in[15];
    const float* ew     = (const float*)d_in[16];
    float* out = (float*)d_out;

    float* ws    = (float*)d_ws;
    float* Gp    = ws;                  // 25*120 = 3000 -> pad 3008
    float* psi2  = Gp + 3008;           // 10560
    float* h2    = psi2 + 10560;        // 10560
    float* DactT = h2 + 10560;          // 95040
    float* T     = DactT + 95040;       // 307200 (16B-aligned: offset 119168 % 4 == 0)

    k_pre<<<886, 256, 0, stream>>>(x, c1w, c1b, c2w, c2b, projw, Dact, DactT,
                                   so3w, Dso3k, psi2, Gp, T);
    k_T2<<<dim3(48, 8), 256, 0, stream>>>(s2w, Gp, Yp, p_w, p_b, T);
    k_so3block<<<NY, NG, 0, stream>>>(T, Ys2, Dact, DactT, h2);
    k_final<<<72, 256, 0, stream>>>(psi2, h2, gamma, beta, ew, out);
}